// Round 2
// baseline (394.108 us; speedup 1.0000x reference)
//
#include <hip/hip_runtime.h>
#include <hip/hip_bf16.h>
#include <math.h>

#define B_ 4
#define T_ 4096
#define D_ 1024
#define E_ 8
#define K_ 2
#define C_ 1537   // int(T*K/E*1.5)+1

typedef short bf16x8 __attribute__((ext_vector_type(8)));
typedef float f32x4 __attribute__((ext_vector_type(4)));

__device__ __forceinline__ unsigned short f2bf(float f) {
    union { float f; unsigned int u; } c; c.f = f;
    unsigned int u = c.u;
    return (unsigned short)((u + 0x7fffu + ((u >> 16) & 1u)) >> 16);
}
__device__ __forceinline__ float bf2f(unsigned short u) {
    union { unsigned int i; float f; } c; c.i = ((unsigned int)u) << 16;
    return c.f;
}
__device__ __forceinline__ void ldsdma16(const void* g, void* l) {
    __builtin_amdgcn_global_load_lds((const __attribute__((address_space(1))) void*)g,
                                     (__attribute__((address_space(3))) void*)l, 16, 0, 0);
}

// ---------------------------------------------------------------------------
// Router: fp64 logits (exact top-k ordering), top-2 softmax, fused x->bf16.
// 16 tokens per block (4 waves x 4 sequential); reduce-scatter shuffle tree.
// ---------------------------------------------------------------------------
__global__ __launch_bounds__(256) void router_kernel(
    const float* __restrict__ x, const float* __restrict__ Wr,
    unsigned short* __restrict__ xbf, int* __restrict__ top_e,
    float* __restrict__ wbuf) {
    __shared__ float wr_s[E_ * D_];
    int tid = threadIdx.x;
    const float4* wr4 = (const float4*)Wr;
    float4* wrs4 = (float4*)wr_s;
    #pragma unroll
    for (int i = 0; i < 8; i++) wrs4[tid + i * 256] = wr4[tid + i * 256];
    __syncthreads();

    int wave = tid >> 6, lane = tid & 63;
    int h5 = (lane >> 5) & 1, h4 = (lane >> 4) & 1, h3 = (lane >> 3) & 1;

    for (int tt = 0; tt < 4; tt++) {
        int token = blockIdx.x * 16 + wave * 4 + tt;
        const float4* xr = (const float4*)(x + (size_t)token * D_) + lane * 4;
        float xs[16];
        #pragma unroll
        for (int i = 0; i < 4; i++) {
            float4 v = xr[i];
            xs[i * 4 + 0] = v.x; xs[i * 4 + 1] = v.y;
            xs[i * 4 + 2] = v.z; xs[i * 4 + 3] = v.w;
        }
        unsigned short xb[16];
        #pragma unroll
        for (int i = 0; i < 16; i++) xb[i] = f2bf(xs[i]);
        uint4* dst = (uint4*)(xbf + (size_t)token * D_ + lane * 16);
        dst[0] = ((uint4*)xb)[0];
        dst[1] = ((uint4*)xb)[1];

        double acc[E_];
        #pragma unroll
        for (int e = 0; e < E_; e++) {
            const float* wp = wr_s + e * D_ + lane * 16;
            double a = 0.0;
            #pragma unroll
            for (int i = 0; i < 16; i++) a += (double)xs[i] * (double)wp[i];
            acc[e] = a;
        }
        // reduce-scatter: fold experts while folding lanes
        double r4[4];
        #pragma unroll
        for (int i = 0; i < 4; i++) {
            double send = h5 ? acc[i] : acc[4 + i];
            double keep = h5 ? acc[4 + i] : acc[i];
            r4[i] = keep + __shfl_xor(send, 32, 64);
        }
        double r2[2];
        #pragma unroll
        for (int i = 0; i < 2; i++) {
            double send = h4 ? r4[i] : r4[2 + i];
            double keep = h4 ? r4[2 + i] : r4[i];
            r2[i] = keep + __shfl_xor(send, 16, 64);
        }
        double r1;
        {
            double send = h3 ? r2[0] : r2[1];
            double keep = h3 ? r2[1] : r2[0];
            r1 = keep + __shfl_xor(send, 8, 64);
        }
        r1 += __shfl_xor(r1, 4, 64);
        r1 += __shfl_xor(r1, 2, 64);
        r1 += __shfl_xor(r1, 1, 64);
        // lane holds full logit of expert h5*4+h4*2+h3; gather all 8
        double le[E_];
        #pragma unroll
        for (int e = 0; e < E_; e++) le[e] = __shfl(r1, e << 3, 64);

        if (lane == 0) {
            int e0 = 0; double v0 = le[0];
            #pragma unroll
            for (int e = 1; e < E_; e++) if (le[e] > v0) { v0 = le[e]; e0 = e; }
            int e1 = -1; double v1 = -1.0e300;
            #pragma unroll
            for (int e = 0; e < E_; e++) if (e != e0 && le[e] > v1) { v1 = le[e]; e1 = e; }
            double ex = exp(v1 - v0);
            top_e[token * 2 + 0] = e0;
            top_e[token * 2 + 1] = e1;
            wbuf[token * 2 + 0] = (float)(1.0 / (1.0 + ex));
            wbuf[token * 2 + 1] = (float)(ex / (1.0 + ex));
        }
    }
}

// ---------------------------------------------------------------------------
// We[e][d][f] fp32 -> We_t[e][f][d] bf16
// ---------------------------------------------------------------------------
__global__ __launch_bounds__(256) void wt_kernel(const float* __restrict__ We,
                                                 unsigned short* __restrict__ wtbf) {
    __shared__ unsigned short tile[64][65];
    int e = blockIdx.x >> 8;
    int t = blockIdx.x & 255;
    int d0 = (t >> 4) * 64, f0 = (t & 15) * 64;
    const float* src = We + ((size_t)e * D_ + d0) * D_ + f0;
    int tid = threadIdx.x;
    #pragma unroll
    for (int i = 0; i < 16; i++) {
        int idx = tid + i * 256;
        int r = idx >> 6, c = idx & 63;
        tile[r][c] = f2bf(src[(size_t)r * D_ + c]);
    }
    __syncthreads();
    unsigned short* dstp = wtbf + ((size_t)e * D_ + f0) * D_ + d0;
    #pragma unroll
    for (int i = 0; i < 16; i++) {
        int idx = tid + i * 256;
        int r = idx >> 6, c = idx & 63;
        dstp[(size_t)r * D_ + c] = tile[c][r];
    }
}

// ---------------------------------------------------------------------------
// Exact (t,k)-order position scan per batch; parallel wave scans.
// Outputs: compacted slot list per (b,e), kept counts, per-slot keep flags.
// ---------------------------------------------------------------------------
__global__ __launch_bounds__(256) void scan_kernel(const int* __restrict__ top_e,
                                                   int* __restrict__ list,
                                                   int* __restrict__ count,
                                                   unsigned char* __restrict__ keep8) {
    int b = blockIdx.x, tid = threadIdx.x;
    const int per = 32;
    __shared__ int cnt[256][9];
    int local[E_];
    #pragma unroll
    for (int e = 0; e < E_; e++) local[e] = 0;
    const int* te = top_e + (size_t)b * 8192 + tid * per;
    int evals[32];
    for (int i = 0; i < per; i++) { evals[i] = te[i]; local[evals[i]]++; }
    #pragma unroll
    for (int e = 0; e < E_; e++) cnt[tid][e] = local[e];
    __syncthreads();

    int wave = tid >> 6, lane = tid & 63;
    #pragma unroll
    for (int ee = 0; ee < 2; ee++) {
        int e = wave * 2 + ee;
        int s0 = cnt[lane * 4 + 0][e], s1 = cnt[lane * 4 + 1][e];
        int s2 = cnt[lane * 4 + 2][e], s3 = cnt[lane * 4 + 3][e];
        int tot = s0 + s1 + s2 + s3;
        int s = tot;
        #pragma unroll
        for (int off = 1; off < 64; off <<= 1) {
            int t2 = __shfl_up(s, off, 64);
            if (lane >= off) s += t2;
        }
        int base = s - tot;  // exclusive
        cnt[lane * 4 + 0][e] = base;
        cnt[lane * 4 + 1][e] = base + s0;
        cnt[lane * 4 + 2][e] = base + s0 + s1;
        cnt[lane * 4 + 3][e] = base + s0 + s1 + s2;
        if (lane == 63) count[b * E_ + e] = min(s, C_);
    }
    __syncthreads();

    int base[E_];
    #pragma unroll
    for (int e = 0; e < E_; e++) base[e] = cnt[tid][e];
    int* lst = list + (size_t)b * E_ * C_;
    unsigned char* kp = keep8 + (size_t)b * 8192;
    for (int i = 0; i < per; i++) {
        int ev = evals[i];
        int p = base[ev]++;
        int slot = tid * per + i;
        kp[slot] = (p < C_) ? 1 : 0;
        if (p < C_) lst[ev * C_ + p] = slot;
    }
}

// ---------------------------------------------------------------------------
// Grouped expert GEMM: 256x128 tile, 4 waves x (128x64), 16x16x32 bf16 MFMA.
// A: global_load_lds (16B) -> double-buffered LDS [rowgroup][kc][row].
// B: direct global->VGPR, prefetched 1 iter ahead. One barrier per kk.
// Epilogue: plain bf16 stores into slot-indexed gather buffer (no atomics).
// ---------------------------------------------------------------------------
__global__ __launch_bounds__(256, 2) void gemm_kernel(
    const unsigned short* __restrict__ xbf, const unsigned short* __restrict__ wtbf,
    const int* __restrict__ list, const int* __restrict__ count,
    unsigned short* __restrict__ gbuf) {
    int cb = blockIdx.x;   // 0..7  col block (128 cols)
    int rb = blockIdx.y;   // 0..6  row block (256 rows)
    int pe = blockIdx.z;   // 0..31 (b,e)
    int b = pe >> 3, e = pe & 7;
    int cnt = count[pe];
    int row0 = rb * 256;
    if (row0 >= cnt) return;
    int rows = min(256, cnt - row0);

    __shared__ unsigned short Abuf[2][256 * 32];  // 2 x 16 KB, [rg][kc][r] chunks
    __shared__ unsigned int rowByte[256];
    __shared__ int slotArr[256];

    int tid = threadIdx.x;
    {
        int slot = list[pe * C_ + row0 + min(tid, rows - 1)];
        slotArr[tid] = (tid < rows) ? slot : -1;
        rowByte[tid] = (unsigned)(((b << 12) + (slot >> 1)) << 11);  // token row * 2048 B
    }
    __syncthreads();

    int wave = tid >> 6, lane = tid & 63;
    int wm = wave >> 1, wn = wave & 1;
    int quad = lane >> 4, mrow = lane & 15;

    const char* xbase = (const char*)xbf;
    unsigned aOff[4];
    #pragma unroll
    for (int g = 0; g < 4; g++) {
        int rg = wave * 4 + g;
        aOff[g] = rowByte[rg * 16 + mrow] + quad * 16;
    }
    const char* wtbase = (const char*)wtbf;
    unsigned bOff[4];
    #pragma unroll
    for (int jt = 0; jt < 4; jt++) {
        int n = cb * 128 + wn * 64 + jt * 16 + mrow;
        bOff[jt] = (unsigned)((((e << 10) + n) << 11) + quad * 16);
    }

    f32x4 acc[8][4];
    #pragma unroll
    for (int i = 0; i < 8; i++)
        #pragma unroll
        for (int j = 0; j < 4; j++) acc[i][j] = (f32x4){0.f, 0.f, 0.f, 0.f};

    // prologue: stage A(0), load B(0)
    #pragma unroll
    for (int g = 0; g < 4; g++)
        ldsdma16(xbase + aOff[g], &Abuf[0][(wave * 4 + g) * 512]);
    uint4 bcur[4], bnext[4];
    #pragma unroll
    for (int jt = 0; jt < 4; jt++) bcur[jt] = *(const uint4*)(wtbase + bOff[jt]);
    __syncthreads();

    for (int kk = 0; kk < 32; kk++) {
        int nb = (kk + 1) & 1;
        if (kk < 31) {
            unsigned ko = (unsigned)(kk + 1) * 64u;
            #pragma unroll
            for (int g = 0; g < 4; g++)
                ldsdma16(xbase + aOff[g] + ko, &Abuf[nb][(wave * 4 + g) * 512]);
            #pragma unroll
            for (int jt = 0; jt < 4; jt++)
                bnext[jt] = *(const uint4*)(wtbase + bOff[jt] + ko);
        }
        const unsigned short* ab = Abuf[kk & 1] + wm * 8 * 512 + lane * 8;
        bf16x8 A8[8];
        #pragma unroll
        for (int it = 0; it < 8; it++)
            A8[it] = *(const bf16x8*)(ab + it * 512);
        #pragma unroll
        for (int it = 0; it < 8; it++)
            #pragma unroll
            for (int jt = 0; jt < 4; jt++)
                acc[it][jt] = __builtin_amdgcn_mfma_f32_16x16x32_bf16(
                    A8[it], *(const bf16x8*)&bcur[jt], acc[it][jt], 0, 0, 0);
        #pragma unroll
        for (int jt = 0; jt < 4; jt++) bcur[jt] = bnext[jt];
        __syncthreads();
    }

    // epilogue: C/D col = mrow (n side), row = quad*4 + r (m side)
    int colbase = cb * 128 + wn * 64 + mrow;
    #pragma unroll
    for (int it = 0; it < 8; it++) {
        int mbase = wm * 128 + it * 16 + quad * 4;
        #pragma unroll
        for (int r = 0; r < 4; r++) {
            int m = mbase + r;
            int slot = slotArr[m];
            if (slot >= 0) {
                unsigned short* grow = gbuf + ((size_t)((b << 13) + slot) << 10);
                #pragma unroll
                for (int jt = 0; jt < 4; jt++)
                    grow[colbase + jt * 16] = f2bf(acc[it][jt][r]);
            }
        }
    }
}

// ---------------------------------------------------------------------------
// Combine: out[t,:] = w0*keep0*g[slot0,:] + w1*keep1*g[slot1,:]
// Fully overwrites out (no memset needed).
// ---------------------------------------------------------------------------
__global__ __launch_bounds__(256) void combine_kernel(
    const unsigned short* __restrict__ gbuf, const float* __restrict__ wbuf,
    const unsigned char* __restrict__ keep8, float* __restrict__ out) {
    int t = blockIdx.x;          // global token 0..16383
    int b = t >> 12;
    int tid = threadIdx.x;
    int kb = (b << 13) + ((t & 4095) << 1);
    float w0 = wbuf[t * 2 + 0] * (float)keep8[kb + 0];
    float w1 = wbuf[t * 2 + 1] * (float)keep8[kb + 1];
    const ushort4* g0 = (const ushort4*)(gbuf + ((size_t)kb << 10)) + tid;
    const ushort4* g1 = (const ushort4*)(gbuf + (((size_t)kb + 1) << 10)) + tid;
    ushort4 a = *g0, c = *g1;
    float4 o;
    o.x = w0 * bf2f(a.x) + w1 * bf2f(c.x);
    o.y = w0 * bf2f(a.y) + w1 * bf2f(c.y);
    o.z = w0 * bf2f(a.z) + w1 * bf2f(c.z);
    o.w = w0 * bf2f(a.w) + w1 * bf2f(c.w);
    ((float4*)(out + (size_t)t * D_))[tid] = o;
}

// ---------------------------------------------------------------------------
extern "C" void kernel_launch(void* const* d_in, const int* in_sizes, int n_in,
                              void* d_out, int out_size, void* d_ws, size_t ws_size,
                              hipStream_t stream) {
    const float* x  = (const float*)d_in[0];
    const float* Wr = (const float*)d_in[1];
    const float* We = (const float*)d_in[2];
    float* out = (float*)d_out;
    char* ws = (char*)d_ws;

    // ws layout (bytes), total ~112.6 MB
    unsigned short* xbf  = (unsigned short*)(ws);              //  33,554,432
    unsigned short* wtbf = (unsigned short*)(ws + 33554432);   //  16,777,216
    unsigned short* gbuf = (unsigned short*)(ws + 50331648);   //  67,108,864
    int*   top_e = (int*)  (ws + 117440512);                   //     131,072
    float* wbuf  = (float*)(ws + 117571584);                   //     131,072
    int*   list  = (int*)  (ws + 117702656);                   //     196,736
    int*   count = (int*)  (ws + 117899392);                   //         128
    unsigned char* keep8 = (unsigned char*)(ws + 117899520);   //      32,768

    router_kernel<<<dim3(B_ * T_ / 16), dim3(256), 0, stream>>>(x, Wr, xbf, top_e, wbuf);
    wt_kernel<<<dim3(E_ * 256), dim3(256), 0, stream>>>(We, wtbf);
    scan_kernel<<<dim3(B_), dim3(256), 0, stream>>>(top_e, list, count, keep8);
    gemm_kernel<<<dim3(8, 7, 32), dim3(256), 0, stream>>>(xbf, wtbf, list, count, gbuf);
    combine_kernel<<<dim3(B_ * T_), dim3(256), 0, stream>>>(gbuf, wbuf, keep8, out);
}

// Round 3
// 353.116 us; speedup vs baseline: 1.1161x; 1.1161x over previous
//
#include <hip/hip_runtime.h>
#include <hip/hip_bf16.h>
#include <math.h>

#define B_ 4
#define T_ 4096
#define D_ 1024
#define E_ 8
#define K_ 2
#define C_ 1537   // int(T*K/E*1.5)+1

typedef short bf16x8 __attribute__((ext_vector_type(8)));
typedef float f32x4 __attribute__((ext_vector_type(4)));

__device__ __forceinline__ unsigned short f2bf(float f) {
    union { float f; unsigned int u; } c; c.f = f;
    unsigned int u = c.u;
    return (unsigned short)((u + 0x7fffu + ((u >> 16) & 1u)) >> 16);
}
__device__ __forceinline__ float bf2f(unsigned short u) {
    union { unsigned int i; float f; } c; c.i = ((unsigned int)u) << 16;
    return c.f;
}
__device__ __forceinline__ void ldsdma16(const void* g, void* l) {
    __builtin_amdgcn_global_load_lds((const __attribute__((address_space(1))) void*)g,
                                     (__attribute__((address_space(3))) void*)l, 16, 0, 0);
}

// ---------------------------------------------------------------------------
// Router: fp64 logits (exact top-k ordering), top-2 softmax, fused x->bf16.
// ---------------------------------------------------------------------------
__global__ __launch_bounds__(256) void router_kernel(
    const float* __restrict__ x, const float* __restrict__ Wr,
    unsigned short* __restrict__ xbf, int* __restrict__ top_e,
    float* __restrict__ wbuf) {
    __shared__ float wr_s[E_ * D_];
    int tid = threadIdx.x;
    const float4* wr4 = (const float4*)Wr;
    float4* wrs4 = (float4*)wr_s;
    #pragma unroll
    for (int i = 0; i < 8; i++) wrs4[tid + i * 256] = wr4[tid + i * 256];
    __syncthreads();

    int wave = tid >> 6, lane = tid & 63;
    int h5 = (lane >> 5) & 1, h4 = (lane >> 4) & 1, h3 = (lane >> 3) & 1;

    for (int tt = 0; tt < 4; tt++) {
        int token = blockIdx.x * 16 + wave * 4 + tt;
        const float4* xr = (const float4*)(x + (size_t)token * D_) + lane * 4;
        float xs[16];
        #pragma unroll
        for (int i = 0; i < 4; i++) {
            float4 v = xr[i];
            xs[i * 4 + 0] = v.x; xs[i * 4 + 1] = v.y;
            xs[i * 4 + 2] = v.z; xs[i * 4 + 3] = v.w;
        }
        unsigned short xb[16];
        #pragma unroll
        for (int i = 0; i < 16; i++) xb[i] = f2bf(xs[i]);
        uint4* dst = (uint4*)(xbf + (size_t)token * D_ + lane * 16);
        dst[0] = ((uint4*)xb)[0];
        dst[1] = ((uint4*)xb)[1];

        double acc[E_];
        #pragma unroll
        for (int e = 0; e < E_; e++) {
            const float* wp = wr_s + e * D_ + lane * 16;
            double a = 0.0;
            #pragma unroll
            for (int i = 0; i < 16; i++) a += (double)xs[i] * (double)wp[i];
            acc[e] = a;
        }
        double r4[4];
        #pragma unroll
        for (int i = 0; i < 4; i++) {
            double send = h5 ? acc[i] : acc[4 + i];
            double keep = h5 ? acc[4 + i] : acc[i];
            r4[i] = keep + __shfl_xor(send, 32, 64);
        }
        double r2[2];
        #pragma unroll
        for (int i = 0; i < 2; i++) {
            double send = h4 ? r4[i] : r4[2 + i];
            double keep = h4 ? r4[2 + i] : r4[i];
            r2[i] = keep + __shfl_xor(send, 16, 64);
        }
        double r1;
        {
            double send = h3 ? r2[0] : r2[1];
            double keep = h3 ? r2[1] : r2[0];
            r1 = keep + __shfl_xor(send, 8, 64);
        }
        r1 += __shfl_xor(r1, 4, 64);
        r1 += __shfl_xor(r1, 2, 64);
        r1 += __shfl_xor(r1, 1, 64);
        double le[E_];
        #pragma unroll
        for (int e = 0; e < E_; e++) le[e] = __shfl(r1, e << 3, 64);

        if (lane == 0) {
            int e0 = 0; double v0 = le[0];
            #pragma unroll
            for (int e = 1; e < E_; e++) if (le[e] > v0) { v0 = le[e]; e0 = e; }
            int e1 = -1; double v1 = -1.0e300;
            #pragma unroll
            for (int e = 0; e < E_; e++) if (e != e0 && le[e] > v1) { v1 = le[e]; e1 = e; }
            double ex = exp(v1 - v0);
            top_e[token * 2 + 0] = e0;
            top_e[token * 2 + 1] = e1;
            wbuf[token * 2 + 0] = (float)(1.0 / (1.0 + ex));
            wbuf[token * 2 + 1] = (float)(ex / (1.0 + ex));
        }
    }
}

// ---------------------------------------------------------------------------
// We[e][d][f] fp32 -> We_t[e][f][d] bf16
// ---------------------------------------------------------------------------
__global__ __launch_bounds__(256) void wt_kernel(const float* __restrict__ We,
                                                 unsigned short* __restrict__ wtbf) {
    __shared__ unsigned short tile[64][65];
    int e = blockIdx.x >> 8;
    int t = blockIdx.x & 255;
    int d0 = (t >> 4) * 64, f0 = (t & 15) * 64;
    const float* src = We + ((size_t)e * D_ + d0) * D_ + f0;
    int tid = threadIdx.x;
    #pragma unroll
    for (int i = 0; i < 16; i++) {
        int idx = tid + i * 256;
        int r = idx >> 6, c = idx & 63;
        tile[r][c] = f2bf(src[(size_t)r * D_ + c]);
    }
    __syncthreads();
    unsigned short* dstp = wtbf + ((size_t)e * D_ + f0) * D_ + d0;
    #pragma unroll
    for (int i = 0; i < 16; i++) {
        int idx = tid + i * 256;
        int r = idx >> 6, c = idx & 63;
        dstp[(size_t)r * D_ + c] = tile[c][r];
    }
}

// ---------------------------------------------------------------------------
// Exact (t,k)-order position scan per batch; parallel wave scans.
// ---------------------------------------------------------------------------
__global__ __launch_bounds__(256) void scan_kernel(const int* __restrict__ top_e,
                                                   int* __restrict__ list,
                                                   int* __restrict__ count,
                                                   unsigned char* __restrict__ keep8) {
    int b = blockIdx.x, tid = threadIdx.x;
    const int per = 32;
    __shared__ int cnt[256][9];
    int local[E_];
    #pragma unroll
    for (int e = 0; e < E_; e++) local[e] = 0;
    const int* te = top_e + (size_t)b * 8192 + tid * per;
    int evals[32];
    for (int i = 0; i < per; i++) { evals[i] = te[i]; local[evals[i]]++; }
    #pragma unroll
    for (int e = 0; e < E_; e++) cnt[tid][e] = local[e];
    __syncthreads();

    int wave = tid >> 6, lane = tid & 63;
    #pragma unroll
    for (int ee = 0; ee < 2; ee++) {
        int e = wave * 2 + ee;
        int s0 = cnt[lane * 4 + 0][e], s1 = cnt[lane * 4 + 1][e];
        int s2 = cnt[lane * 4 + 2][e], s3 = cnt[lane * 4 + 3][e];
        int tot = s0 + s1 + s2 + s3;
        int s = tot;
        #pragma unroll
        for (int off = 1; off < 64; off <<= 1) {
            int t2 = __shfl_up(s, off, 64);
            if (lane >= off) s += t2;
        }
        int base = s - tot;
        cnt[lane * 4 + 0][e] = base;
        cnt[lane * 4 + 1][e] = base + s0;
        cnt[lane * 4 + 2][e] = base + s0 + s1;
        cnt[lane * 4 + 3][e] = base + s0 + s1 + s2;
        if (lane == 63) count[b * E_ + e] = min(s, C_);
    }
    __syncthreads();

    int base[E_];
    #pragma unroll
    for (int e = 0; e < E_; e++) base[e] = cnt[tid][e];
    int* lst = list + (size_t)b * E_ * C_;
    unsigned char* kp = keep8 + (size_t)b * 8192;
    for (int i = 0; i < per; i++) {
        int ev = evals[i];
        int p = base[ev]++;
        int slot = tid * per + i;
        kp[slot] = (p < C_) ? 1 : 0;
        if (p < C_) lst[ev * C_ + p] = slot;
    }
}

// ---------------------------------------------------------------------------
// Grouped expert GEMM, m97 structure: 128x128 tile, BK=64, single-buffer LDS,
// both operands via global_load_lds (16B), 2 barriers / K-iter, 32 MFMA / iter
// per wave. A rows gathered (per-lane DMA addresses). Plain bf16 epilogue.
// ---------------------------------------------------------------------------
__global__ __launch_bounds__(256) void gemm_kernel(
    const unsigned short* __restrict__ xbf, const unsigned short* __restrict__ wtbf,
    const int* __restrict__ list, const int* __restrict__ count,
    unsigned short* __restrict__ gbuf) {
    int cb = blockIdx.x;   // 0..7   col block (128)
    int rb = blockIdx.y;   // 0..12  row block (128)
    int pe = blockIdx.z;   // 0..31  (b,e)
    int b = pe >> 3, e = pe & 7;
    int cnt = count[pe];
    int row0 = rb * 128;
    if (row0 >= cnt) return;
    int rows = min(128, cnt - row0);

    __shared__ unsigned short As[128 * 64];  // 16 KB, [g][lane] DMA order
    __shared__ unsigned short Bs[128 * 64];  // 16 KB
    __shared__ unsigned int rowByte[128];
    __shared__ int slotArr[128];

    int tid = threadIdx.x;
    if (tid < 128) {
        int slot = list[pe * C_ + row0 + min(tid, rows - 1)];
        slotArr[tid] = (tid < rows) ? slot : -1;
        rowByte[tid] = (unsigned)(((b << 12) + (slot >> 1)) << 11);  // token row * 2048 B
    }
    __syncthreads();

    int wave = tid >> 6, lane = tid & 63;
    int quad = lane >> 4, mrow = lane & 15;
    int wm = wave >> 1, wn = wave & 1;

    // issue g (0..15): row = (g&7)*16 + mrow, k-chunk = (g>>3)*4 + quad
    // LDS dst = buf + g*512 shorts (+ lane*16B by HW); global 64B-contig per row
    const char* xbase = (const char*)xbf;
    const char* wtbase = (const char*)wtbf;
    unsigned aAddr[4], bAddr[4];
    #pragma unroll
    for (int i = 0; i < 4; i++) {
        int g = wave * 4 + i;
        int row = (g & 7) * 16 + mrow;
        unsigned kcb = (unsigned)(((g >> 3) * 4 + quad) * 16);
        aAddr[i] = rowByte[row] + kcb;
        int nrow = cb * 128 + row;
        bAddr[i] = (unsigned)((((e << 10) + nrow) << 11) + kcb);
    }

    f32x4 acc[4][4];
    #pragma unroll
    for (int i = 0; i < 4; i++)
        #pragma unroll
        for (int j = 0; j < 4; j++) acc[i][j] = (f32x4){0.f, 0.f, 0.f, 0.f};

    for (int kk = 0; kk < 16; kk++) {
        unsigned ko = (unsigned)kk * 128u;   // 64 shorts per row per iter
        __syncthreads();                      // LDS free to overwrite
        #pragma unroll
        for (int i = 0; i < 4; i++) {
            int g = wave * 4 + i;
            ldsdma16(xbase + aAddr[i] + ko, &As[g * 512]);
            ldsdma16(wtbase + bAddr[i] + ko, &Bs[g * 512]);
        }
        __syncthreads();                      // drain: tile ready
        #pragma unroll
        for (int ks = 0; ks < 2; ks++) {
            bf16x8 af[4], bfv[4];
            #pragma unroll
            for (int it = 0; it < 4; it++)
                af[it] = *(const bf16x8*)(As + (ks * 8 + wm * 4 + it) * 512 + lane * 8);
            #pragma unroll
            for (int jt = 0; jt < 4; jt++)
                bfv[jt] = *(const bf16x8*)(Bs + (ks * 8 + wn * 4 + jt) * 512 + lane * 8);
            #pragma unroll
            for (int it = 0; it < 4; it++)
                #pragma unroll
                for (int jt = 0; jt < 4; jt++)
                    acc[it][jt] = __builtin_amdgcn_mfma_f32_16x16x32_bf16(
                        af[it], bfv[jt], acc[it][jt], 0, 0, 0);
        }
    }

    // epilogue: C/D col = mrow (n), row = quad*4 + r (m)
    int colbase = cb * 128 + wn * 64 + mrow;
    #pragma unroll
    for (int it = 0; it < 4; it++) {
        int mbase = wm * 64 + it * 16 + quad * 4;
        #pragma unroll
        for (int r = 0; r < 4; r++) {
            int slot = slotArr[mbase + r];
            if (slot >= 0) {
                unsigned short* grow = gbuf + ((size_t)((b << 13) + slot) << 10);
                #pragma unroll
                for (int jt = 0; jt < 4; jt++)
                    grow[colbase + jt * 16] = f2bf(acc[it][jt][r]);
            }
        }
    }
}

// ---------------------------------------------------------------------------
// Combine: out[t,:] = w0*keep0*g[slot0,:] + w1*keep1*g[slot1,:]
// ---------------------------------------------------------------------------
__global__ __launch_bounds__(256) void combine_kernel(
    const unsigned short* __restrict__ gbuf, const float* __restrict__ wbuf,
    const unsigned char* __restrict__ keep8, float* __restrict__ out) {
    int t = blockIdx.x;
    int b = t >> 12;
    int tid = threadIdx.x;
    int kb = (b << 13) + ((t & 4095) << 1);
    float w0 = wbuf[t * 2 + 0] * (float)keep8[kb + 0];
    float w1 = wbuf[t * 2 + 1] * (float)keep8[kb + 1];
    const ushort4* g0 = (const ushort4*)(gbuf + ((size_t)kb << 10)) + tid;
    const ushort4* g1 = (const ushort4*)(gbuf + (((size_t)kb + 1) << 10)) + tid;
    ushort4 a = *g0, c = *g1;
    float4 o;
    o.x = w0 * bf2f(a.x) + w1 * bf2f(c.x);
    o.y = w0 * bf2f(a.y) + w1 * bf2f(c.y);
    o.z = w0 * bf2f(a.z) + w1 * bf2f(c.z);
    o.w = w0 * bf2f(a.w) + w1 * bf2f(c.w);
    ((float4*)(out + (size_t)t * D_))[tid] = o;
}

// ---------------------------------------------------------------------------
extern "C" void kernel_launch(void* const* d_in, const int* in_sizes, int n_in,
                              void* d_out, int out_size, void* d_ws, size_t ws_size,
                              hipStream_t stream) {
    const float* x  = (const float*)d_in[0];
    const float* Wr = (const float*)d_in[1];
    const float* We = (const float*)d_in[2];
    float* out = (float*)d_out;
    char* ws = (char*)d_ws;

    unsigned short* xbf  = (unsigned short*)(ws);              //  33,554,432
    unsigned short* wtbf = (unsigned short*)(ws + 33554432);   //  16,777,216
    unsigned short* gbuf = (unsigned short*)(ws + 50331648);   //  67,108,864
    int*   top_e = (int*)  (ws + 117440512);                   //     131,072
    float* wbuf  = (float*)(ws + 117571584);                   //     131,072
    int*   list  = (int*)  (ws + 117702656);                   //     196,736
    int*   count = (int*)  (ws + 117899392);                   //         128
    unsigned char* keep8 = (unsigned char*)(ws + 117899520);   //      32,768

    router_kernel<<<dim3(B_ * T_ / 16), dim3(256), 0, stream>>>(x, Wr, xbf, top_e, wbuf);
    wt_kernel<<<dim3(E_ * 256), dim3(256), 0, stream>>>(We, wtbf);
    scan_kernel<<<dim3(B_), dim3(256), 0, stream>>>(top_e, list, count, keep8);
    gemm_kernel<<<dim3(8, 13, 32), dim3(256), 0, stream>>>(xbf, wtbf, list, count, gbuf);
    combine_kernel<<<dim3(B_ * T_), dim3(256), 0, stream>>>(gbuf, wbuf, keep8, out);
}